// Round 20
// baseline (55.400 us; speedup 1.0000x reference)
//
#include <hip/hip_runtime.h>

#define N_ 8
#define C_ 64
#define P_ 4096

typedef float f32x4 __attribute__((ext_vector_type(4)));
typedef float f32x2 __attribute__((ext_vector_type(2)));
typedef short bf16x8 __attribute__((ext_vector_type(8)));

__device__ __forceinline__ unsigned short f2bf(float f) {
  unsigned int u = __builtin_bit_cast(unsigned int, f);
  u = (u + 0x7fffu + ((u >> 16) & 1u)) >> 16;  // RNE
  return (unsigned short)u;
}

// Schraudolph fast 2^x (FMA pipe). pos/tot share the approx -> ratio error
// cancels; proven absmax ~0 at threshold 0.166 (R17/R18).
__device__ __forceinline__ float exp2appr(float x) {
  const int i = (int)__builtin_fmaf(x, 8388608.0f, 1064992209.0f);
  return __builtin_bit_cast(float, i);
}

// ONE fused kernel. Block = 256p x 512q of one n (grid 1024 = 8n x 16pc x 8qc,
// n = blockIdx&7 for XCD L2 locality on the raw inputs).
// Phase 1 (fill): read raw f32 A/B columns (coalesced; L3-resident 16.8MB),
//   compute row norms, pack normalized bf16: B -> LDS (64KB, XOR-swizzled
//   rows), A -> per-wave register fragments (rgb side pre-scaled 10*log2e).
//   Norm work is recomputed redundantly per block (24x total) -- trivial
//   VALU vs the launch+intermediate+per-iter-staging it deletes.
// Phase 2 (compute): 8 iterations of pure {ds_read + MFMA + packed-
//   Schraudolph epilogue}. ZERO global traffic, ZERO barriers, no waitcnt
//   games -- the per-iter global-fetch dependency that pinned R10..R19 at
//   ~28us is gone by construction.
// Phase 3 (finalize, fused): per-block {pos,tot} -> unique par[] slots via
//   atomicAdd (coherent point; NO threadfence -- R15's poison), vmcnt(0),
//   ticket; last block atomic-reads all slots, computes loss, writes out.
__global__ void __launch_bounds__(256) pixcon_fused(
    const float* __restrict__ rgb, const float* __restrict__ ir,
    float* __restrict__ par, unsigned* __restrict__ cnt,
    float* __restrict__ out) {
  const int lin = blockIdx.x;
  const int n = lin & 7;
  const int local = lin >> 3;
  const int pc = local & 15;  // 16 p-chunks of 256
  const int qc = local >> 4;  // 8 q-chunks of 512
  const int tid = threadIdx.x;
  const int lane = tid & 63;
  const int wid = tid >> 6;
  const int p0 = pc * 256;
  const int q0 = qc * 512;
  const int pbase = p0 + wid * 64;
  const float* Araw = rgb + (size_t)n * C_ * P_;  // [C][P]
  const float* Braw = ir + (size_t)n * C_ * P_;   // [C][P]

  __shared__ __align__(16) unsigned short bsm[512 * 64];  // 64 KB
  __shared__ float ssqA[256];
  __shared__ float sb[8];
  __shared__ float fp[8], ft[8];
  __shared__ unsigned rank_s;

  // ---- A row norms: thread t -> row p0+t (coalesced across threads) ----
  {
    float ss = 0.f;
    const float* colp = Araw + p0 + tid;
#pragma unroll 8
    for (int c = 0; c < 64; ++c) {
      const float x = colp[(size_t)c * P_];
      ss = __builtin_fmaf(x, x, ss);
    }
    ssqA[tid] = ss;
  }

  // ---- B rows: thread t -> rows q0+2t, q0+2t+1 (float2 coalesced).
  //      Pass 1: sum-of-squares. Pass 2: scale+pack -> LDS swizzled. ----
  {
    const float* colq = Braw + q0 + 2 * tid;
    float ss0 = 0.f, ss1 = 0.f;
#pragma unroll 8
    for (int c = 0; c < 64; ++c) {
      const f32x2 v = *reinterpret_cast<const f32x2*>(colq + (size_t)c * P_);
      ss0 = __builtin_fmaf(v[0], v[0], ss0);
      ss1 = __builtin_fmaf(v[1], v[1], ss1);
    }
    const float inv0 = 1.0f / fmaxf(sqrtf(ss0), 1e-12f);
    const float inv1 = 1.0f / fmaxf(sqrtf(ss1), 1e-12f);
    const int r0 = 2 * tid, r1 = 2 * tid + 1;
    unsigned short* w0 = bsm + r0 * 64;
    unsigned short* w1 = bsm + r1 * 64;
#pragma unroll 1
    for (int g = 0; g < 8; ++g) {
      bf16x8 pk0, pk1;
#pragma unroll
      for (int j = 0; j < 8; ++j) {
        const f32x2 v =
            *reinterpret_cast<const f32x2*>(colq + (size_t)(g * 8 + j) * P_);
        pk0[j] = (short)f2bf(v[0] * inv0);
        pk1[j] = (short)f2bf(v[1] * inv1);
      }
      *reinterpret_cast<bf16x8*>(w0 + ((g ^ (r0 & 7)) * 8)) = pk0;
      *reinterpret_cast<bf16x8*>(w1 + ((g ^ (r1 & 7)) * 8)) = pk1;
    }
  }

  __syncthreads();  // ssqA + bsm ready

  // ---- A fragments: normalize+pack into registers (one-time strided) ----
  const int r16 = lane & 15;
  const int kofs = (lane >> 4) * 8;
  const float SC = 14.4269504088896340736f;  // 10*log2(e), folded into A
  float invA[4];
#pragma unroll
  for (int mi = 0; mi < 4; ++mi) {
    const int rrel = wid * 64 + mi * 16 + r16;
    invA[mi] = SC / fmaxf(sqrtf(ssqA[rrel]), 1e-12f);
  }
  bf16x8 af[2][4];
#pragma unroll
  for (int ks = 0; ks < 2; ++ks)
#pragma unroll
    for (int mi = 0; mi < 4; ++mi) {
      const float* src = Araw + pbase + mi * 16 + r16;
      bf16x8 pk;
#pragma unroll
      for (int j = 0; j < 8; ++j) {
        const float x = src[(size_t)(ks * 32 + kofs + j) * P_];
        pk[j] = (short)f2bf(x * invA[mi]);
      }
      af[ks][mi] = pk;
    }

  // ---- Compute: 8 tiles, all LDS-resident. No barriers, no global. ----
  const f32x4 zc = (f32x4)(0.f);
  f32x2 ch2[8];
#pragma unroll
  for (int k = 0; k < 8; ++k) ch2[k] = (f32x2)(0.f);
  float pos = 0.f;
  const int col = lane & 15;
  const int rowb = (lane >> 4) * 4;

#pragma unroll 1
  for (int t = 0; t < 8; ++t) {
    const unsigned short* bp = bsm + t * 64 * 64;
    bf16x8 bf_[2][4];
#pragma unroll
    for (int ks = 0; ks < 2; ++ks)
#pragma unroll
      for (int ni = 0; ni < 4; ++ni) {
        const int row = ni * 16 + r16;
        const int seg = ks * 4 + (lane >> 4);
        bf_[ks][ni] = *reinterpret_cast<const bf16x8*>(
            bp + row * 64 + ((seg ^ (lane & 7)) * 8));
      }

    f32x4 acc[4][4];
    __builtin_amdgcn_s_setprio(1);
#pragma unroll
    for (int mi = 0; mi < 4; ++mi)
#pragma unroll
      for (int ni = 0; ni < 4; ++ni)
        acc[mi][ni] = __builtin_amdgcn_mfma_f32_16x16x32_bf16(
            af[0][mi], bf_[0][ni], zc, 0, 0, 0);
#pragma unroll
    for (int mi = 0; mi < 4; ++mi)
#pragma unroll
      for (int ni = 0; ni < 4; ++ni)
        acc[mi][ni] = __builtin_amdgcn_mfma_f32_16x16x32_bf16(
            af[1][mi], bf_[1][ni], acc[mi][ni], 0, 0, 0);
    __builtin_amdgcn_s_setprio(0);

    // Packed Schraudolph exp2 into 16 chains (8 f32x2).
#pragma unroll
    for (int mi = 0; mi < 4; ++mi)
#pragma unroll
      for (int ni = 0; ni < 4; ++ni) {
        const int base = ((mi * 4 + ni) & 3) * 2;
        const f32x4 v = acc[mi][ni];
        f32x2 a0, a1;
        a0[0] = v[0]; a0[1] = v[1];
        a1[0] = v[2]; a1[1] = v[3];
        const f32x2 f0 = a0 * 8388608.0f + (f32x2)(1064992209.0f);
        const f32x2 f1 = a1 * 8388608.0f + (f32x2)(1064992209.0f);
        f32x2 e0, e1;
        e0[0] = __builtin_bit_cast(float, (int)f0[0]);
        e0[1] = __builtin_bit_cast(float, (int)f0[1]);
        e1[0] = __builtin_bit_cast(float, (int)f1[0]);
        e1[1] = __builtin_bit_cast(float, (int)f1[1]);
        ch2[base] += e0;
        ch2[base + 1] += e1;
      }
    const int qb = q0 + t * 64;
    if (pbase == qb) {  // diagonal subtile
#pragma unroll
      for (int mi = 0; mi < 4; ++mi)
#pragma unroll
        for (int r = 0; r < 4; ++r)
          if (rowb + r == col) pos += exp2appr(acc[mi][mi][r]);
    }
  }

  f32x2 sum2 = ((ch2[0] + ch2[1]) + (ch2[2] + ch2[3])) +
               ((ch2[4] + ch2[5]) + (ch2[6] + ch2[7]));
  float tot = sum2[0] + sum2[1];
#pragma unroll
  for (int off = 32; off > 0; off >>= 1) {
    tot += __shfl_down(tot, off);
    pos += __shfl_down(pos, off);
  }
  if (lane == 0) { sb[wid * 2] = pos; sb[wid * 2 + 1] = tot; }
  __syncthreads();

  // ---- Fused finalize: unique-slot atomics + ticket; last block reduces.
  if (tid == 0) {
    const float pp = sb[0] + sb[2] + sb[4] + sb[6];
    const float tt = sb[1] + sb[3] + sb[5] + sb[7];
    const int slot = n * 128 + pc * 8 + qc;  // unique per block
    atomicAdd(&par[slot], pp);
    atomicAdd(&par[1024 + slot], tt);
    asm volatile("s_waitcnt vmcnt(0)" ::: "memory");  // atomics at L2 point
    rank_s = atomicAdd(cnt, 1u);
  }
  __syncthreads();
  if (rank_s == 1023u) {  // all other blocks' atomics completed
    const int nn = tid >> 5;  // 0..7
    const int ch = tid & 31;  // 0..31
    float sp_ = 0.f, st_ = 0.f;
#pragma unroll
    for (int k = 0; k < 4; ++k) {
      sp_ += atomicAdd(&par[nn * 128 + ch * 4 + k], 0.0f);        // coherent read
      st_ += atomicAdd(&par[1024 + nn * 128 + ch * 4 + k], 0.0f);
    }
#pragma unroll
    for (int off = 16; off > 0; off >>= 1) {
      sp_ += __shfl_down(sp_, off);
      st_ += __shfl_down(st_, off);
    }
    if (ch == 0) { fp[nn] = sp_; ft[nn] = st_; }
    __syncthreads();
    if (tid == 0) {
      float loss = 0.f;
#pragma unroll
      for (int k = 0; k < 8; ++k) loss += -logf(fp[k] / (ft[k] + 1e-6f));
      out[0] = loss * 0.125f;
    }
  }
}

extern "C" void kernel_launch(void* const* d_in, const int* in_sizes, int n_in,
                              void* d_out, int out_size, void* d_ws, size_t ws_size,
                              hipStream_t stream) {
  const float* rgb = (const float*)d_in[0];
  const float* ir = (const float*)d_in[1];
  float* out = (float*)d_out;

  float* par = (float*)d_ws;                 // 2048 floats (pos|tot slots)
  unsigned* cnt = (unsigned*)(par + 2048);   // ticket

  hipMemsetAsync(d_ws, 0, 2048 * sizeof(float) + sizeof(unsigned), stream);

  pixcon_fused<<<1024, 256, 0, stream>>>(rgb, ir, par, cnt, out);
}

// Round 21
// 46.389 us; speedup vs baseline: 1.1943x; 1.1943x over previous
//
#include <hip/hip_runtime.h>

#define N_ 8
#define C_ 64
#define P_ 4096

typedef float f32x4 __attribute__((ext_vector_type(4)));
typedef float f32x2 __attribute__((ext_vector_type(2)));
typedef short bf16x8 __attribute__((ext_vector_type(8)));

__device__ __forceinline__ unsigned short f2bf(float f) {
  unsigned int u = __builtin_bit_cast(unsigned int, f);
  u = (u + 0x7fffu + ((u >> 16) & 1u)) >> 16;  // RNE
  return (unsigned short)u;
}

// Schraudolph fast 2^x (FMA pipe). pos/tot share the approx -> ratio error
// cancels; proven absmax ~0 at threshold 0.166 (R17-R20).
__device__ __forceinline__ float exp2appr(float x) {
  const int i = (int)__builtin_fmaf(x, 8388608.0f, 1064992209.0f);
  return __builtin_bit_cast(float, i);
}

// Kernel 1: L2-normalize along C, write bf16 transposed to [N][P][C].
// Split-C (2 threads per p). rgb pre-scaled by 10*log2(e); ir rows
// 16B-group XOR-swizzled (g ^= p&7) matching the gemm's fragment offsets.
__global__ void __launch_bounds__(256) norm_transpose(
    const float* __restrict__ rgb, const float* __restrict__ ir,
    unsigned short* __restrict__ rgbnT, unsigned short* __restrict__ irnT) {
  const int tid = threadIdx.x;
  const int half = tid >> 7;
  const int pl = tid & 127;
  const int gp = blockIdx.x * 128 + pl;
  const int n = gp >> 12;
  const int p = gp & (P_ - 1);
  const float* src = (blockIdx.y == 0) ? rgb : ir;
  unsigned short* dst = (blockIdx.y == 0) ? rgbnT : irnT;
  const float SC = 14.4269504088896340736f;  // 10*log2(e)
  const float* col = src + (size_t)n * C_ * P_ + (size_t)(half * 32) * P_ + p;
  float v[32];
  float ss = 0.f;
#pragma unroll
  for (int c = 0; c < 32; ++c) {
    v[c] = col[(size_t)c * P_];
    ss += v[c] * v[c];
  }
  __shared__ float ssq[2][128];
  ssq[half][pl] = ss;
  __syncthreads();
  const float tot = ssq[0][pl] + ssq[1][pl];
  float inv = 1.0f / fmaxf(sqrtf(tot), 1e-12f);
  if (blockIdx.y == 0) inv *= SC;
  const int gx = (blockIdx.y == 0) ? 0 : (p & 7);
  unsigned short* o = dst + (size_t)gp * C_;
#pragma unroll
  for (int gi = 0; gi < 4; ++gi) {
    bf16x8 pack;
#pragma unroll
    for (int j = 0; j < 8; ++j) pack[j] = (short)f2bf(v[gi * 8 + j] * inv);
    const int gg = half * 4 + gi;
    *reinterpret_cast<bf16x8*>(o + (gg ^ gx) * 8) = pack;
  }
}

// Kernel 2: fused gemm + finalize. Block = 256p x 512q of one n
// (grid 1024 = 8n x 16pc x 8qc; n = blockIdx&7 for XCD L2 locality).
// Phase 1: load the PACKED B-stripe (512 rows x 64c bf16 = 64KB; written
//   once by norm_transpose -> only 67MB aggregate L2 traffic, vs R20's
//   2.1GB raw-B redundancy) into LDS via 16 global_load_lds (linear dest,
//   zero write conflicts -- R20's 524K-conflict fill is gone). ONE
//   vmcnt(0) + barrier total. A-frags to registers (packed, linear rows).
// Phase 2: R20's compute core -- 8 iterations of pure {ds_read + MFMA +
//   packed-Schraudolph}. Zero global traffic, zero barriers, no waitcnt
//   games (the per-iter global dependency that pinned R10..R19 at ~28us
//   does not exist).
// Phase 3: R20's proven fused finalize (unique-slot atomicAdd, vmcnt(0),
//   ticket; NO threadfence -- R15's poison). Last block reduces + writes.
__global__ void __launch_bounds__(256) gemm_fused(
    const unsigned short* __restrict__ aT, const unsigned short* __restrict__ bT,
    float* __restrict__ par, unsigned* __restrict__ cnt,
    float* __restrict__ out) {
  const int lin = blockIdx.x;
  const int n = lin & 7;
  const int local = lin >> 3;
  const int pc = local & 15;  // 16 p-chunks of 256
  const int qc = local >> 4;  // 8 q-chunks of 512
  const int tid = threadIdx.x;
  const int lane = tid & 63;
  const int wid = tid >> 6;
  const int pbase = pc * 256 + wid * 64;
  const int q0 = qc * 512;
  const unsigned short* A = aT + (size_t)n * P_ * C_;  // [P][C] linear
  const unsigned short* B = bT + (size_t)n * P_ * C_;  // [P][C] swizzled rows
  const int r16 = lane & 15;
  const int kofs = (lane >> 4) * 8;

  __shared__ __align__(16) unsigned short bsm[512 * 64];  // 64 KB
  __shared__ float sb[8];
  __shared__ float fp[8], ft[8];
  __shared__ unsigned rank_s;

  // ---- Phase 1: stage packed B-stripe (64KB) into LDS. ----
  {
    const unsigned short* src = B + (size_t)q0 * C_;
#pragma unroll
    for (int r = 0; r < 16; ++r) {
      __builtin_amdgcn_global_load_lds(
          (const __attribute__((address_space(1))) void*)(src +
                                                          (size_t)(r * 256 + tid) * 8),
          (__attribute__((address_space(3))) void*)(bsm +
                                                    (r * 256 + wid * 64) * 8),
          16, 0, 0);
    }
  }

  // A fragments while B stages (independent, packed linear rows).
  bf16x8 af[2][4];
#pragma unroll
  for (int ks = 0; ks < 2; ++ks)
#pragma unroll
    for (int mi = 0; mi < 4; ++mi)
      af[ks][mi] = *reinterpret_cast<const bf16x8*>(
          A + (size_t)(pbase + mi * 16 + r16) * C_ + ks * 32 + kofs);

  asm volatile("s_waitcnt vmcnt(0)" ::: "memory");
  __builtin_amdgcn_s_barrier();  // bsm fully resident; the ONLY barrier

  // ---- Phase 2: 8 LDS-only tiles. ----
  const f32x4 zc = (f32x4)(0.f);
  f32x2 ch2[8];
#pragma unroll
  for (int k = 0; k < 8; ++k) ch2[k] = (f32x2)(0.f);
  float pos = 0.f;
  const int col = lane & 15;
  const int rowb = (lane >> 4) * 4;

#pragma unroll 1
  for (int t = 0; t < 8; ++t) {
    const unsigned short* bp = bsm + t * 64 * 64;
    bf16x8 bf_[2][4];
#pragma unroll
    for (int ks = 0; ks < 2; ++ks)
#pragma unroll
      for (int ni = 0; ni < 4; ++ni) {
        const int row = ni * 16 + r16;
        const int seg = ks * 4 + (lane >> 4);
        bf_[ks][ni] = *reinterpret_cast<const bf16x8*>(
            bp + row * 64 + ((seg ^ (lane & 7)) * 8));
      }

    f32x4 acc[4][4];
    __builtin_amdgcn_s_setprio(1);
#pragma unroll
    for (int mi = 0; mi < 4; ++mi)
#pragma unroll
      for (int ni = 0; ni < 4; ++ni)
        acc[mi][ni] = __builtin_amdgcn_mfma_f32_16x16x32_bf16(
            af[0][mi], bf_[0][ni], zc, 0, 0, 0);
#pragma unroll
    for (int mi = 0; mi < 4; ++mi)
#pragma unroll
      for (int ni = 0; ni < 4; ++ni)
        acc[mi][ni] = __builtin_amdgcn_mfma_f32_16x16x32_bf16(
            af[1][mi], bf_[1][ni], acc[mi][ni], 0, 0, 0);
    __builtin_amdgcn_s_setprio(0);

    // Packed Schraudolph exp2 into 16 chains (8 f32x2).
#pragma unroll
    for (int mi = 0; mi < 4; ++mi)
#pragma unroll
      for (int ni = 0; ni < 4; ++ni) {
        const int base = ((mi * 4 + ni) & 3) * 2;
        const f32x4 v = acc[mi][ni];
        f32x2 a0, a1;
        a0[0] = v[0]; a0[1] = v[1];
        a1[0] = v[2]; a1[1] = v[3];
        const f32x2 f0 = a0 * 8388608.0f + (f32x2)(1064992209.0f);
        const f32x2 f1 = a1 * 8388608.0f + (f32x2)(1064992209.0f);
        f32x2 e0, e1;
        e0[0] = __builtin_bit_cast(float, (int)f0[0]);
        e0[1] = __builtin_bit_cast(float, (int)f0[1]);
        e1[0] = __builtin_bit_cast(float, (int)f1[0]);
        e1[1] = __builtin_bit_cast(float, (int)f1[1]);
        ch2[base] += e0;
        ch2[base + 1] += e1;
      }
    const int qb = q0 + t * 64;
    if (pbase == qb) {  // diagonal subtile
#pragma unroll
      for (int mi = 0; mi < 4; ++mi)
#pragma unroll
        for (int r = 0; r < 4; ++r)
          if (rowb + r == col) pos += exp2appr(acc[mi][mi][r]);
    }
  }

  f32x2 sum2 = ((ch2[0] + ch2[1]) + (ch2[2] + ch2[3])) +
               ((ch2[4] + ch2[5]) + (ch2[6] + ch2[7]));
  float tot = sum2[0] + sum2[1];
#pragma unroll
  for (int off = 32; off > 0; off >>= 1) {
    tot += __shfl_down(tot, off);
    pos += __shfl_down(pos, off);
  }
  if (lane == 0) { sb[wid * 2] = pos; sb[wid * 2 + 1] = tot; }
  __syncthreads();

  // ---- Phase 3: fused finalize (R20-proven). ----
  if (tid == 0) {
    const float pp = sb[0] + sb[2] + sb[4] + sb[6];
    const float tt = sb[1] + sb[3] + sb[5] + sb[7];
    const int slot = n * 128 + pc * 8 + qc;  // unique per block
    atomicAdd(&par[slot], pp);
    atomicAdd(&par[1024 + slot], tt);
    asm volatile("s_waitcnt vmcnt(0)" ::: "memory");  // atomics at L2 point
    rank_s = atomicAdd(cnt, 1u);
  }
  __syncthreads();
  if (rank_s == 1023u) {  // all other blocks' atomics completed
    const int nn = tid >> 5;  // 0..7
    const int ch = tid & 31;  // 0..31
    float sp_ = 0.f, st_ = 0.f;
#pragma unroll
    for (int k = 0; k < 4; ++k) {
      sp_ += atomicAdd(&par[nn * 128 + ch * 4 + k], 0.0f);  // coherent read
      st_ += atomicAdd(&par[1024 + nn * 128 + ch * 4 + k], 0.0f);
    }
#pragma unroll
    for (int off = 16; off > 0; off >>= 1) {
      sp_ += __shfl_down(sp_, off);
      st_ += __shfl_down(st_, off);
    }
    if (ch == 0) { fp[nn] = sp_; ft[nn] = st_; }
    __syncthreads();
    if (tid == 0) {
      float loss = 0.f;
#pragma unroll
      for (int k = 0; k < 8; ++k) loss += -logf(fp[k] / (ft[k] + 1e-6f));
      out[0] = loss * 0.125f;
    }
  }
}

extern "C" void kernel_launch(void* const* d_in, const int* in_sizes, int n_in,
                              void* d_out, int out_size, void* d_ws, size_t ws_size,
                              hipStream_t stream) {
  const float* rgb = (const float*)d_in[0];
  const float* ir = (const float*)d_in[1];
  float* out = (float*)d_out;

  unsigned short* rgbnT = (unsigned short*)d_ws;              // 4 MB
  unsigned short* irnT = rgbnT + (size_t)N_ * P_ * C_;        // 4 MB
  float* par = (float*)(irnT + (size_t)N_ * P_ * C_);         // 8 KB
  unsigned* cnt = (unsigned*)(par + 2048);                    // 4 B

  hipMemsetAsync(par, 0, 2048 * sizeof(float) + sizeof(unsigned), stream);

  dim3 g1(N_ * P_ / 128, 2);
  norm_transpose<<<g1, 256, 0, stream>>>(rgb, ir, rgbnT, irnT);

  gemm_fused<<<1024, 256, 0, stream>>>(rgbnT, irnT, par, cnt, out);
}

// Round 22
// 38.644 us; speedup vs baseline: 1.4336x; 1.2004x over previous
//
#include <hip/hip_runtime.h>

#define N_ 8
#define C_ 64
#define P_ 4096

typedef float f32x4 __attribute__((ext_vector_type(4)));
typedef float f32x2 __attribute__((ext_vector_type(2)));
typedef short bf16x8 __attribute__((ext_vector_type(8)));

__device__ __forceinline__ unsigned short f2bf(float f) {
  unsigned int u = __builtin_bit_cast(unsigned int, f);
  u = (u + 0x7fffu + ((u >> 16) & 1u)) >> 16;  // RNE
  return (unsigned short)u;
}

// Schraudolph fast 2^x (FMA pipe). pos/tot share the approx -> ratio error
// cancels; proven absmax ~0 at threshold 0.166 (R17-R21).
__device__ __forceinline__ float exp2appr(float x) {
  const int i = (int)__builtin_fmaf(x, 8388608.0f, 1064992209.0f);
  return __builtin_bit_cast(float, i);
}

// Kernel 1: L2-normalize along C, write bf16 transposed to [N][P][C].
// Split-C (2 threads per p). rgb pre-scaled by 10*log2(e); ir rows
// 16B-group XOR-swizzled (g ^= p&7) matching the gemm's fragment offsets.
__global__ void __launch_bounds__(256) norm_transpose(
    const float* __restrict__ rgb, const float* __restrict__ ir,
    unsigned short* __restrict__ rgbnT, unsigned short* __restrict__ irnT) {
  const int tid = threadIdx.x;
  const int half = tid >> 7;
  const int pl = tid & 127;
  const int gp = blockIdx.x * 128 + pl;
  const int n = gp >> 12;
  const int p = gp & (P_ - 1);
  const float* src = (blockIdx.y == 0) ? rgb : ir;
  unsigned short* dst = (blockIdx.y == 0) ? rgbnT : irnT;
  const float SC = 14.4269504088896340736f;  // 10*log2(e)
  const float* col = src + (size_t)n * C_ * P_ + (size_t)(half * 32) * P_ + p;
  float v[32];
  float ss = 0.f;
#pragma unroll
  for (int c = 0; c < 32; ++c) {
    v[c] = col[(size_t)c * P_];
    ss += v[c] * v[c];
  }
  __shared__ float ssq[2][128];
  ssq[half][pl] = ss;
  __syncthreads();
  const float tot = ssq[0][pl] + ssq[1][pl];
  float inv = 1.0f / fmaxf(sqrtf(tot), 1e-12f);
  if (blockIdx.y == 0) inv *= SC;
  const int gx = (blockIdx.y == 0) ? 0 : (p & 7);
  unsigned short* o = dst + (size_t)gp * C_;
#pragma unroll
  for (int gi = 0; gi < 4; ++gi) {
    bf16x8 pack;
#pragma unroll
    for (int j = 0; j < 8; ++j) pack[j] = (short)f2bf(v[gi * 8 + j] * inv);
    const int gg = half * 4 + gi;
    *reinterpret_cast<bf16x8*>(o + (gg ^ gx) * 8) = pack;
  }
}

// Async global->LDS: 8KB tile (64 q-rows x 64 c), 256 threads x 2 x 16B.
__device__ __forceinline__ void stage_tile(const unsigned short* src,
                                           unsigned short* dst, int tid,
                                           int wid) {
#pragma unroll
  for (int r = 0; r < 2; ++r) {
    __builtin_amdgcn_global_load_lds(
        (const __attribute__((address_space(1))) void*)(src +
                                                        (size_t)(r * 256 + tid) * 8),
        (__attribute__((address_space(3))) void*)(dst + (r * 256 + wid * 64) * 8),
        16, 0, 0);
  }
}

// Kernel 2: 256p x 1024q (16 q-tiles of 64), 4 waves x 64 p-rows.
// GRID = 512 BLOCKS (was 1024) -- the single variable vs R18. Rationale:
// across 21 rounds, gemm time fell monotonically with block count at fixed
// work (8192 blk -> 67us, 2048 -> 43.5, 1024 -> ~28-30); every in-block
// schedule variant was null. Each block carries a serial head (A-frag
// strided loads + ring prologue, ~1-2us cold latency) amortized here over
// 2x the work, with 2 co-resident blocks/CU (ring-4 LDS = 33KB) and 2
// sequential generations instead of 4.
// Schedule: ring-4 LDS staged by global_load_lds, COUNTED vmcnt(4) +
// single raw s_barrier per iter (R10/R11, proven). Epilogue: packed
// Schraudolph into 16 chains (R18, VGPR=112 -> 4-waves/SIMD tier).
__global__ void __launch_bounds__(256) gemm_exp_reduce(
    const unsigned short* __restrict__ aT, const unsigned short* __restrict__ bT,
    float* __restrict__ partials) {
  const int lin = blockIdx.x;  // [0,512)
  const int n = lin & 7;
  const int local = lin >> 3;  // [0,64)
  const int pc = local & 15;   // 16 p-chunks of 256
  const int qc = local >> 4;   // 4 q-chunks of 1024
  const int tid = threadIdx.x;
  const int lane = tid & 63;
  const int wid = tid >> 6;  // 4 waves
  const int pbase = pc * 256 + wid * 64;
  const int q0 = qc * 1024;
  const unsigned short* A = aT + (size_t)n * P_ * C_;  // [P][C] linear
  const unsigned short* B = bT + (size_t)n * P_ * C_;  // [P][C] swizzled rows
  const int r16 = lane & 15;
  const int kofs = (lane >> 4) * 8;

  __shared__ __align__(16) unsigned short bs0[64 * 64];
  __shared__ __align__(16) unsigned short bs1[64 * 64];
  __shared__ __align__(16) unsigned short bs2[64 * 64];
  __shared__ __align__(16) unsigned short bs3[64 * 64];

  // A fragments: resident in registers for the whole kernel (32 VGPR).
  bf16x8 af[2][4];
#pragma unroll
  for (int ks = 0; ks < 2; ++ks)
#pragma unroll
    for (int mi = 0; mi < 4; ++mi)
      af[ks][mi] = *reinterpret_cast<const bf16x8*>(
          A + (size_t)(pbase + mi * 16 + r16) * C_ + ks * 32 + kofs);

  // Prologue: fill 3 of 4 ring slots (6 outstanding loads/thread).
  stage_tile(B + (size_t)(q0 + 0 * 64) * C_, bs0, tid, wid);
  stage_tile(B + (size_t)(q0 + 1 * 64) * C_, bs1, tid, wid);
  stage_tile(B + (size_t)(q0 + 2 * 64) * C_, bs2, tid, wid);

  unsigned short *pcur = bs0, *pnx1 = bs1, *pnx2 = bs2, *pnx3 = bs3;

  const f32x4 zc = (f32x4)(0.f);  // constant zero C-in (never written)
  f32x2 ch2[8];                   // 16 scalar chains as 8 packed pairs
#pragma unroll
  for (int k = 0; k < 8; ++k) ch2[k] = (f32x2)(0.f);
  float pos = 0.f;
  const int col = lane & 15;
  const int rowb = (lane >> 4) * 4;

#pragma unroll 1
  for (int t = 0; t < 16; ++t) {
    // Wait for the OLDEST stage only (tile t): 4 newer loads stay in flight.
    asm volatile("s_waitcnt vmcnt(4)" ::: "memory");
    __builtin_amdgcn_sched_barrier(0);
    __builtin_amdgcn_s_barrier();  // tile-t landed everywhere; all waves done
                                   // reading buf[(t-1)%4] (passed prev iter)

    // Stage tile (t+3)&15 into pnx3 = buf[(t-1)%4], freed by this barrier.
    // Wrapped (t+3>15) stages are dummies into dead buffers (uniform vmcnt).
    int s = t + 3;
    if (s >= 16) s -= 16;
    stage_tile(B + (size_t)(q0 + s * 64) * C_, pnx3, tid, wid);

    // LDS -> B fragments (swizzled read matches pre-swizzled global rows)
    const unsigned short* bp = pcur;
    bf16x8 bf_[2][4];
#pragma unroll
    for (int ks = 0; ks < 2; ++ks)
#pragma unroll
      for (int ni = 0; ni < 4; ++ni) {
        const int row = ni * 16 + r16;
        const int seg = ks * 4 + (lane >> 4);
        bf_[ks][ni] = *reinterpret_cast<const bf16x8*>(
            bp + row * 64 + ((seg ^ (lane & 7)) * 8));
      }

    f32x4 acc[4][4];
    __builtin_amdgcn_s_setprio(1);
#pragma unroll
    for (int mi = 0; mi < 4; ++mi)
#pragma unroll
      for (int ni = 0; ni < 4; ++ni)
        acc[mi][ni] = __builtin_amdgcn_mfma_f32_16x16x32_bf16(
            af[0][mi], bf_[0][ni], zc, 0, 0, 0);
#pragma unroll
    for (int mi = 0; mi < 4; ++mi)
#pragma unroll
      for (int ni = 0; ni < 4; ++ni)
        acc[mi][ni] = __builtin_amdgcn_mfma_f32_16x16x32_bf16(
            af[1][mi], bf_[1][ni], acc[mi][ni], 0, 0, 0);
    __builtin_amdgcn_s_setprio(0);

    // Epilogue: packed Schraudolph exp2 into 16 chains (8 f32x2).
#pragma unroll
    for (int mi = 0; mi < 4; ++mi)
#pragma unroll
      for (int ni = 0; ni < 4; ++ni) {
        const int base = ((mi * 4 + ni) & 3) * 2;
        const f32x4 v = acc[mi][ni];
        f32x2 a0, a1;
        a0[0] = v[0]; a0[1] = v[1];
        a1[0] = v[2]; a1[1] = v[3];
        const f32x2 f0 = a0 * 8388608.0f + (f32x2)(1064992209.0f);
        const f32x2 f1 = a1 * 8388608.0f + (f32x2)(1064992209.0f);
        f32x2 e0, e1;
        e0[0] = __builtin_bit_cast(float, (int)f0[0]);
        e0[1] = __builtin_bit_cast(float, (int)f0[1]);
        e1[0] = __builtin_bit_cast(float, (int)f1[0]);
        e1[1] = __builtin_bit_cast(float, (int)f1[1]);
        ch2[base] += e0;
        ch2[base + 1] += e1;
      }
    const int qb = q0 + t * 64;
    if (pbase == qb) {  // diagonal subtile
#pragma unroll
      for (int mi = 0; mi < 4; ++mi)
#pragma unroll
        for (int r = 0; r < 4; ++r)
          if (rowb + r == col) pos += exp2appr(acc[mi][mi][r]);
    }

    // Rotate ring (top barrier of t+1 protects the next stage target).
    unsigned short* tmp = pcur;
    pcur = pnx1;
    pnx1 = pnx2;
    pnx2 = pnx3;
    pnx3 = tmp;
  }

  f32x2 sum2 = ((ch2[0] + ch2[1]) + (ch2[2] + ch2[3])) +
               ((ch2[4] + ch2[5]) + (ch2[6] + ch2[7]));
  float tot = sum2[0] + sum2[1];
#pragma unroll
  for (int off = 32; off > 0; off >>= 1) {
    tot += __shfl_down(tot, off);
    pos += __shfl_down(pos, off);
  }
  __shared__ float sb[8];
  if (lane == 0) { sb[wid * 2] = pos; sb[wid * 2 + 1] = tot; }
  __syncthreads();  // one full drain here is fine (once per block)
  if (tid == 0) {
    const float pp = sb[0] + sb[2] + sb[4] + sb[6];
    const float tt = sb[1] + sb[3] + sb[5] + sb[7];
    const int bid = n * 64 + pc * 4 + qc;
    partials[bid * 2] = pp;
    partials[bid * 2 + 1] = tt;
  }
}

// Kernel 3: reduce 64 partial pairs per n, compute loss. One pass.
__global__ void __launch_bounds__(1024) finalize(
    const float* __restrict__ partials, float* __restrict__ out) {
  const int tid = threadIdx.x;
  const int lane = tid & 63, wid = tid >> 6;  // 16 waves; 2 waves per n
  __shared__ float sp[16], st[16], sl[8];
  const int n = tid >> 7;
  const int i = tid & 127;
  float p = 0.f, t = 0.f;
  if (i < 64) {
    p = partials[(n * 64 + i) * 2];
    t = partials[(n * 64 + i) * 2 + 1];
  }
#pragma unroll
  for (int off = 32; off > 0; off >>= 1) {
    p += __shfl_down(p, off);
    t += __shfl_down(t, off);
  }
  if (lane == 0) { sp[wid] = p; st[wid] = t; }
  __syncthreads();
  if (tid < 8) {
    const float pp = sp[2 * tid] + sp[2 * tid + 1];
    const float tt = st[2 * tid] + st[2 * tid + 1];
    sl[tid] = -logf(pp / (tt + 1e-6f));
  }
  __syncthreads();
  if (tid == 0) {
    float loss = 0.f;
#pragma unroll
    for (int k = 0; k < 8; ++k) loss += sl[k];
    out[0] = loss * (1.0f / N_);
  }
}

extern "C" void kernel_launch(void* const* d_in, const int* in_sizes, int n_in,
                              void* d_out, int out_size, void* d_ws, size_t ws_size,
                              hipStream_t stream) {
  const float* rgb = (const float*)d_in[0];
  const float* ir = (const float*)d_in[1];
  float* out = (float*)d_out;

  unsigned short* rgbnT = (unsigned short*)d_ws;              // 4 MB
  unsigned short* irnT = rgbnT + (size_t)N_ * P_ * C_;        // 4 MB
  float* partials = (float*)(irnT + (size_t)N_ * P_ * C_);    // 4 KB

  dim3 g1(N_ * P_ / 128, 2);
  norm_transpose<<<g1, 256, 0, stream>>>(rgb, ir, rgbnT, irnT);

  gemm_exp_reduce<<<512, 256, 0, stream>>>(rgbnT, irnT, partials);

  finalize<<<1, 1024, 0, stream>>>(partials, out);
}